// Round 13
// baseline (987.644 us; speedup 1.0000x reference)
//
#include <hip/hip_runtime.h>
#include <hip/hip_bf16.h>
#include <stdint.h>

// TreeLSTM on MI355X (gfx950) — v10: barrier-free per-level wave pipeline.
// Each WAVE owns 16 nodes of one level end-to-end: A = node data (h_cat or
// emb row) loaded 16B/lane straight from global in MFMA fragment layout,
// B = packed bf16 weights streamed from L2, epilogue + fused in-register
// logits (16-lane shuffle reduce). No LDS, no __syncthreads anywhere.
// Children are local slots 2i,2i+1 via per-split id-chase kernels.
// Inter-level h/c (bf16) lives in d_ws; forest processed in 1/2/4 splits
// chosen from ws_size (need 204/102/51 MB). If ws < 51 MB: fused fallback
// (v7, measured 903us). Weight packing idempotent -> replay/poison-proof.

typedef __attribute__((ext_vector_type(8))) short short8;
typedef __attribute__((ext_vector_type(4))) float f32x4;

__device__ __forceinline__ unsigned short f2bf(float x) {
    unsigned u = __float_as_uint(x);
    u += 0x7fffu + ((u >> 16) & 1u);   // round-to-nearest-even
    return (unsigned short)(u >> 16);
}
__device__ __forceinline__ float bf2f(unsigned short b) {
    return __uint_as_float(((unsigned)b) << 16);
}
__device__ __forceinline__ float rcp_fast(float x) { return __builtin_amdgcn_rcpf(x); }
__device__ __forceinline__ float sigm(float x) { return rcp_fast(1.f + __expf(-x)); }
__device__ __forceinline__ float tanh_fast(float x) {
    float e = __expf(2.f * x);
    return (e - 1.f) * rcp_fast(e + 1.f);
}

// ---------------------------------------------------------------------------
// Pack W_iou (384x256) -> Wl ; [U_iou (384x256); U_f (256x256)] -> Wc (640x256)
__global__ __launch_bounds__(256)
void prep_kernel(const float* __restrict__ W_iou,
                 const float* __restrict__ U_iou,
                 const float* __restrict__ U_f,
                 unsigned short* __restrict__ Wl,
                 unsigned short* __restrict__ Wc)
{
    const int i = blockIdx.x * 256 + threadIdx.x;   // grid covers 98304
    if (i < 98304) {
        Wl[i] = f2bf(W_iou[i]);
        Wc[i] = f2bf(U_iou[i]);
    }
    if (i < 65536) {
        Wc[98304 + i] = f2bf(U_f[i]);
    }
}

// ---------------------------------------------------------------------------
// Id chase: dst[2i],dst[2i+1] = cp[ src[i] or srcBase+i ] — makes level-l
// local slot i's children be local slots 2i,2i+1 in the level below.
__global__ __launch_bounds__(256)
void chase_kernel(const int2* __restrict__ cp, const int* __restrict__ src,
                  int srcBase, int n, int* __restrict__ dst)
{
    const int i = blockIdx.x * 256 + threadIdx.x;
    if (i < n) {
        const int s = src ? src[i] : srcBase + i;
        const int2 c = cp[s];
        dst[2 * i]     = c.x;
        dst[2 * i + 1] = c.y;
    }
}

// ---------------------------------------------------------------------------
// One wave = 16 nodes of one level, fully independent, no LDS/barriers.
// mfma(A=nodes, B=W): A row = lane&15 (node), B col = lane&15 (n = p+j*128),
// k = ks*32 + (lane>>4)*8. D: col(lane&15)=p, rows (lane>>4)*4+r = node.
// Loop pbase over 8 p-slices; acc[NCOL] per slice; logits accumulate in regs.
template<int NCOL, bool LEAF, bool STORE_HC>
__global__ __launch_bounds__(256)
void wave_level(const unsigned short* __restrict__ Wg,  // [NCOL*128][256] bf16
                const int*  __restrict__ idlist,        // local->global (or null)
                int idbase,
                const int*  __restrict__ leafx,         // LEAF only
                const float* __restrict__ emb,          // LEAF only
                const unsigned short* __restrict__ hprev,
                const unsigned short* __restrict__ cprev,
                unsigned short* __restrict__ hout,
                unsigned short* __restrict__ cout,
                const float* __restrict__ b_iou,
                const float* __restrict__ b_f,
                const float* __restrict__ W_lin,
                const float* __restrict__ b_lin,
                float* __restrict__ out, int segOff, int nnodes)
{
    const int lane = threadIdx.x & 63;
    const int nb   = (blockIdx.x * 4 + (threadIdx.x >> 6)) * 16;  // local base
    if (nb >= nnodes) return;
    const int lrow = lane & 15;
    const int lk   = lane >> 4;

    // ---- A fragments: node (lane&15)'s 16B at k = ks*32 + lk*8, all 8 ks ----
    short8 aN[8];
    if (LEAF) {
        const int li = idlist ? idlist[nb + lrow] : idbase + nb + lrow;
        const int gi = leafx[li];
        const float* er = emb + (size_t)gi * 256;
        #pragma unroll
        for (int ks = 0; ks < 8; ++ks) {
            const float4 a = *reinterpret_cast<const float4*>(er + ks * 32 + lk * 8);
            const float4 b = *reinterpret_cast<const float4*>(er + ks * 32 + lk * 8 + 4);
            short8 v;
            v[0]=(short)f2bf(a.x); v[1]=(short)f2bf(a.y);
            v[2]=(short)f2bf(a.z); v[3]=(short)f2bf(a.w);
            v[4]=(short)f2bf(b.x); v[5]=(short)f2bf(b.y);
            v[6]=(short)f2bf(b.z); v[7]=(short)f2bf(b.w);
            aN[ks] = v;
        }
    } else {
        #pragma unroll
        for (int ks = 0; ks < 8; ++ks) {
            const int child = 2 * (nb + lrow) + (ks >= 4 ? 1 : 0);
            aN[ks] = *reinterpret_cast<const short8*>(
                hprev + (size_t)child * 128 + (ks & 3) * 32 + lk * 8);
        }
    }

    // global out-ids for the 4 nodes this lane owns in D
    int gidr[4];
    #pragma unroll
    for (int r = 0; r < 4; ++r) {
        const int i = nb + lk * 4 + r;
        gidr[r] = idlist ? idlist[i] : idbase + i;
    }

    float lgt[5][4];
    #pragma unroll
    for (int cl = 0; cl < 5; ++cl)
        #pragma unroll
        for (int r = 0; r < 4; ++r) lgt[cl][r] = 0.f;

    for (int pb = 0; pb < 128; pb += 16) {
        f32x4 acc[NCOL];
        #pragma unroll
        for (int j = 0; j < NCOL; ++j) acc[j] = (f32x4){0.f, 0.f, 0.f, 0.f};

        #pragma unroll
        for (int ks = 0; ks < 8; ++ks) {
            short8 bW[NCOL];
            #pragma unroll
            for (int j = 0; j < NCOL; ++j)
                bW[j] = *reinterpret_cast<const short8*>(
                    Wg + (size_t)(j * 128 + pb + lrow) * 256 + ks * 32 + lk * 8);
            #pragma unroll
            for (int j = 0; j < NCOL; ++j)
                acc[j] = __builtin_amdgcn_mfma_f32_16x16x32_bf16(
                    aN[ks], bW[j], acc[j], 0, 0, 0);
        }

        const int p = pb + lrow;
        const float bi = b_iou[p], bo = b_iou[128 + p], bu = b_iou[256 + p];
        float bf0 = 0.f, bf1 = 0.f;
        if (NCOL == 5) { bf0 = b_f[p]; bf1 = b_f[128 + p]; }
        float wl[5];
        #pragma unroll
        for (int cl = 0; cl < 5; ++cl) wl[cl] = W_lin[cl * 128 + p];

        #pragma unroll
        for (int r = 0; r < 4; ++r) {
            const int i = nb + lk * 4 + r;
            const float iv = acc[0][r] + bi;
            const float ov = acc[1][r] + bo;
            const float uv = acc[2][r] + bu;
            float csum = 0.f;
            if (NCOL == 5) {
                const float c0 = bf2f(cprev[(size_t)(2 * i) * 128 + p]);
                const float c1 = bf2f(cprev[(size_t)(2 * i + 1) * 128 + p]);
                csum = sigm(acc[3][r] + bf0) * c0 + sigm(acc[4][r] + bf1) * c1;
            }
            const float cv = sigm(iv) * tanh_fast(uv) + csum;
            const float hv = sigm(ov) * tanh_fast(cv);
            if (STORE_HC) {
                hout[(size_t)i * 128 + p] = f2bf(hv);
                cout[(size_t)i * 128 + p] = f2bf(cv);
            }
            #pragma unroll
            for (int cl = 0; cl < 5; ++cl) lgt[cl][r] += hv * wl[cl];
        }
    }

    // ---- logits: butterfly-reduce over the 16-lane p-group, then write ----
    #pragma unroll
    for (int cl = 0; cl < 5; ++cl)
        #pragma unroll
        for (int r = 0; r < 4; ++r) {
            float d = lgt[cl][r];
            d += __shfl_xor(d, 1);
            d += __shfl_xor(d, 2);
            d += __shfl_xor(d, 4);
            d += __shfl_xor(d, 8);
            lgt[cl][r] = d;
        }
    if (lrow < 5) {
        const float bl = b_lin[lrow];
        #pragma unroll
        for (int r = 0; r < 4; ++r) {
            float v = (lrow == 0) ? lgt[0][r] : (lrow == 1) ? lgt[1][r]
                    : (lrow == 2) ? lgt[2][r] : (lrow == 3) ? lgt[3][r] : lgt[4][r];
            out[(size_t)(segOff + gidr[r]) * 5 + lrow] = v + bl;
        }
    }
}

// ===========================================================================
// Fallback (ws too small): v7 fused subtree kernel — measured 903us, passed.
// ===========================================================================
#define FB_THREADS 512

template<int NCOL, int G, int CW, bool WC>
__device__ __forceinline__ void fb_level_step(
    const unsigned short* __restrict__ Wg,
    const unsigned char* Blds, unsigned char* h_out, unsigned short* cAr,
    const float* __restrict__ b_iou, const float* __restrict__ b_f,
    int w, int lrow, int lk, int slotBase, int mrows)
{
    const int q0 = w * 16;
    const unsigned char* wbase = reinterpret_cast<const unsigned char*>(Wg)
                               + (q0 + lrow) * 512 + lk * 16;
    f32x4 acc[NCOL][G];
    #pragma unroll
    for (int j = 0; j < NCOL; ++j)
        #pragma unroll
        for (int g = 0; g < G; ++g) acc[j][g] = (f32x4){0.f, 0.f, 0.f, 0.f};
    #pragma unroll
    for (int ks = 0; ks < 8; ++ks) {
        short8 aW[NCOL];
        #pragma unroll
        for (int j = 0; j < NCOL; ++j)
            aW[j] = *reinterpret_cast<const short8*>(wbase + j * 65536 + ks * 64);
        #pragma unroll
        for (int g = 0; g < G; ++g) {
            const int row = g * 16 + lrow;
            const int chunk = (ks * 4 + lk) ^ (row & 7);
            short8 bN = *reinterpret_cast<const short8*>(
                Blds + row * 512 + (chunk << 4));
            #pragma unroll
            for (int j = 0; j < NCOL; ++j)
                acc[j][g] = __builtin_amdgcn_mfma_f32_16x16x32_bf16(
                    aW[j], bN, acc[j][g], 0, 0, 0);
        }
    }
    #pragma unroll
    for (int g = 0; g < G; ++g) {
        const int mlB = g * 16 + lrow;
        if (mlB < mrows) {
            const int ml = slotBase + mlB;
            #pragma unroll
            for (int r = 0; r < 4; ++r) {
                const int p = q0 + lk * 4 + r;
                float iv = acc[0][g][r] + b_iou[p];
                float ov = acc[1][g][r] + b_iou[128 + p];
                float uv = acc[2][g][r] + b_iou[256 + p];
                float csum = 0.f;
                if (NCOL == 5) {
                    float f0 = acc[3][g][r] + b_f[p];
                    float f1 = acc[4][g][r] + b_f[128 + p];
                    const int cb = p * 66 + CW * mlB;
                    csum = sigm(f0) * bf2f(cAr[cb]) + sigm(f1) * bf2f(cAr[cb + CW / 2]);
                }
                float cv = sigm(iv) * tanh_fast(uv) + csum;
                float hv = sigm(ov) * tanh_fast(cv);
                if (WC) cAr[p * 66 + CW * ml] = f2bf(cv);
                const int jr = ml >> 1;
                const int q = (ml & 1) * 16 + (p >> 3);
                *reinterpret_cast<unsigned short*>(
                    h_out + jr * 512 + ((q ^ (jr & 7)) << 4) + (p & 7) * 2) = f2bf(hv);
            }
        }
    }
}

__device__ __forceinline__ void fb_logits_emit(
    const unsigned char* h_lds, int M, const int* idsLds, int idBase,
    int segOff, const float* __restrict__ W_lin, const float* __restrict__ b_lin,
    float* __restrict__ out, int t)
{
    const int s = t >> 2, sub = t & 3;
    if (s >= M) return;
    float hv[32];
    const int j = s >> 1;
    #pragma unroll
    for (int qq = 0; qq < 4; ++qq) {
        const int q = (s & 1) * 16 + sub * 4 + qq;
        short8 v = *reinterpret_cast<const short8*>(
            h_lds + j * 512 + ((q ^ (j & 7)) << 4));
        #pragma unroll
        for (int e = 0; e < 8; ++e) hv[qq * 8 + e] = bf2f((unsigned short)v[e]);
    }
    const int gid = idsLds ? idsLds[s] : (idBase + s);
    float dots[5];
    #pragma unroll
    for (int cl = 0; cl < 5; ++cl) {
        const float* wr = W_lin + cl * 128 + sub * 32;
        float d = 0.f;
        #pragma unroll
        for (int k = 0; k < 32; ++k) d += hv[k] * wr[k];
        d += __shfl_xor(d, 1);
        d += __shfl_xor(d, 2);
        dots[cl] = d;
    }
    if (sub == 0) {
        float* op = out + (size_t)(segOff + gid) * 5;
        #pragma unroll
        for (int cl = 0; cl < 5; ++cl) op[cl] = dots[cl] + b_lin[cl];
    }
}

__global__ __launch_bounds__(FB_THREADS, 4)
void fb_tree_kernel(const int*  __restrict__ leaf_x,
                    const int2* __restrict__ cpairs,
                    const float* __restrict__ emb,
                    const unsigned short* __restrict__ Wl,
                    const unsigned short* __restrict__ Wc,
                    const float* __restrict__ b_iou,
                    const float* __restrict__ b_f,
                    const float* __restrict__ W_lin,
                    const float* __restrict__ b_lin,
                    float* __restrict__ out)
{
    __shared__ __align__(16) unsigned char arena[49664];
    __shared__ int ids0[64], ids1[32], ids2[16], tok[64];
    const int t = threadIdx.x, lane = t & 63, w = t >> 6;
    const int lrow = lane & 15, lk = lane >> 4;
    const int blk3 = blockIdx.x * 8;
    if (t < 8)  { int2 p = cpairs[196608 + blk3 + t]; ids2[2*t] = p.x; ids2[2*t+1] = p.y; }
    __syncthreads();
    if (t < 16) { int2 p = cpairs[131072 + ids2[t]];  ids1[2*t] = p.x; ids1[2*t+1] = p.y; }
    __syncthreads();
    if (t < 32) { int2 p = cpairs[ids1[t]];           ids0[2*t] = p.x; ids0[2*t+1] = p.y; }
    __syncthreads();
    if (t < 64) { tok[t] = leaf_x[ids0[t]]; }
    __syncthreads();
    unsigned char*  X0  = arena;
    unsigned char*  h0  = arena + 16384;
    unsigned short* cAr = (unsigned short*)(arena + 32768);
    unsigned char*  h1  = arena;
    unsigned char*  h2  = arena + 16384;
    unsigned char*  h3  = arena + 8192;
    #pragma unroll 1
    for (int half = 0; half < 2; ++half) {
        {
            const int c = t & 31, r0 = t >> 5;
            #pragma unroll
            for (int rr = 0; rr < 2; ++rr) {
                const int r = r0 + rr * 16;
                const int gi = tok[half * 32 + r];
                const float4* src = reinterpret_cast<const float4*>(
                    emb + (size_t)gi * 256 + c * 8);
                float4 a = src[0], b = src[1];
                short8 v;
                v[0]=(short)f2bf(a.x); v[1]=(short)f2bf(a.y);
                v[2]=(short)f2bf(a.z); v[3]=(short)f2bf(a.w);
                v[4]=(short)f2bf(b.x); v[5]=(short)f2bf(b.y);
                v[6]=(short)f2bf(b.z); v[7]=(short)f2bf(b.w);
                *reinterpret_cast<short8*>(X0 + r * 512 + ((c ^ (r & 7)) << 4)) = v;
            }
        }
        __syncthreads();
        fb_level_step<3, 2, 1, true>(Wl, X0, h0, cAr, b_iou, b_f,
                                     w, lrow, lk, half * 32, 32);
        __syncthreads();
    }
    fb_logits_emit(h0, 64, ids0, 0, 0, W_lin, b_lin, out, t);
    fb_level_step<5, 2, 2, true>(Wc, h0, h1, cAr, b_iou, b_f, w, lrow, lk, 0, 32);
    __syncthreads();
    fb_logits_emit(h1, 32, ids1, 0, 262144, W_lin, b_lin, out, t);
    fb_level_step<5, 1, 4, true>(Wc, h1, h2, cAr, b_iou, b_f, w, lrow, lk, 0, 16);
    __syncthreads();
    fb_logits_emit(h2, 16, ids2, 0, 393216, W_lin, b_lin, out, t);
    fb_level_step<5, 1, 8, false>(Wc, h2, h3, cAr, b_iou, b_f, w, lrow, lk, 0, 8);
    __syncthreads();
    fb_logits_emit(h3, 8, nullptr, blk3, 458752, W_lin, b_lin, out, t);
}

// ---------------------------------------------------------------------------
extern "C" void kernel_launch(void* const* d_in, const int* in_sizes, int n_in,
                              void* d_out, int out_size, void* d_ws, size_t ws_size,
                              hipStream_t stream)
{
    const int*   leaf_x = (const int*)d_in[0];
    const int*   child  = (const int*)d_in[1];
    const float* emb    = (const float*)d_in[2];
    const float* W_iou  = (const float*)d_in[3];
    const float* U_iou  = (const float*)d_in[4];
    const float* b_iou  = (const float*)d_in[5];
    const float* U_f    = (const float*)d_in[6];
    const float* b_f    = (const float*)d_in[7];
    const float* W_lin  = (const float*)d_in[8];
    const float* b_lin  = (const float*)d_in[9];
    float* out = (float*)d_out;

    char* ws = (char*)d_ws;
    unsigned short* Wl = (unsigned short*)ws;                 // 192 KiB
    unsigned short* Wc = (unsigned short*)(ws + 196608);      // 320 KiB

    // workspace need for split count s: ids + h0/c0 + h1/c1 (h2/c2 alias h0/c0)
    auto need = [](int s) -> size_t {
        const size_t n3 = 32768u / s, n2 = 2 * n3, n1 = 2 * n2, n0 = 2 * n1;
        size_t off = 524288;
        off += (n0 + n1 + n2) * 4;            // ids
        off = (off + 255) & ~(size_t)255;
        off += (n0 + n0 + n1 + n1) * 256;     // h0,c0,h1,c1 (256 B per node)
        return off;
    };
    int s = 0;
    if      (ws_size >= need(1)) s = 1;
    else if (ws_size >= need(2)) s = 2;
    else if (ws_size >= need(4)) s = 4;

    prep_kernel<<<384, 256, 0, stream>>>(W_iou, U_iou, U_f, Wl, Wc);

    if (s == 0) {
        fb_tree_kernel<<<4096, FB_THREADS, 0, stream>>>(
            leaf_x, (const int2*)child, emb, Wl, Wc,
            b_iou, b_f, W_lin, b_lin, out);
        return;
    }

    const int n3 = 32768 / s, n2 = 2 * n3, n1 = 2 * n2, n0 = 2 * n1;
    size_t off = 524288;
    int* ids0 = (int*)(ws + off); off += (size_t)n0 * 4;
    int* ids1 = (int*)(ws + off); off += (size_t)n1 * 4;
    int* ids2 = (int*)(ws + off); off += (size_t)n2 * 4;
    off = (off + 255) & ~(size_t)255;
    unsigned short* h0 = (unsigned short*)(ws + off); off += (size_t)n0 * 256;
    unsigned short* c0 = (unsigned short*)(ws + off); off += (size_t)n0 * 256;
    unsigned short* h1 = (unsigned short*)(ws + off); off += (size_t)n1 * 256;
    unsigned short* c1 = (unsigned short*)(ws + off);
    unsigned short* h2 = h0;   // leaf buffers dead once L1 written
    unsigned short* c2 = c0;

    const int2* cp = (const int2*)child;
    for (int sp = 0; sp < s; ++sp) {
        const int r3 = sp * n3;
        chase_kernel<<<(n3 + 255) / 256, 256, 0, stream>>>(cp + 196608, nullptr, r3, n3, ids2);
        chase_kernel<<<(n2 + 255) / 256, 256, 0, stream>>>(cp + 131072, ids2, 0, n2, ids1);
        chase_kernel<<<(n1 + 255) / 256, 256, 0, stream>>>(cp,          ids1, 0, n1, ids0);

        wave_level<3, true, true><<<n0 / 64, 256, 0, stream>>>(
            Wl, ids0, 0, leaf_x, emb, nullptr, nullptr, h0, c0,
            b_iou, b_f, W_lin, b_lin, out, 0, n0);
        wave_level<5, false, true><<<n1 / 64, 256, 0, stream>>>(
            Wc, ids1, 0, nullptr, nullptr, h0, c0, h1, c1,
            b_iou, b_f, W_lin, b_lin, out, 262144, n1);
        wave_level<5, false, true><<<n2 / 64, 256, 0, stream>>>(
            Wc, ids2, 0, nullptr, nullptr, h1, c1, h2, c2,
            b_iou, b_f, W_lin, b_lin, out, 393216, n2);
        wave_level<5, false, false><<<n3 / 64, 256, 0, stream>>>(
            Wc, nullptr, r3, nullptr, nullptr, h2, c2, nullptr, nullptr,
            b_iou, b_f, W_lin, b_lin, out, 458752, n3);
    }
}

// Round 14
// 981.761 us; speedup vs baseline: 1.0060x; 1.0060x over previous
//
#include <hip/hip_runtime.h>
#include <hip/hip_bf16.h>
#include <stdint.h>

// TreeLSTM on MI355X (gfx950) — v11: barrier-free wave pipeline + LDS
// store-staging. Each WAVE owns 16 nodes of one level end-to-end. v10's
// epilogue issued 512 scalar 2B global stores per wave (vmcnt saturation +
// sector write-amplification inside the MFMA loop). v11 stages h/c in a
// private 8KB LDS slice per wave (ds_write_b16, no vmcnt) and flushes once
// at the end as 8x ds_read_b128 + 8x coalesced global_store_dwordx4.
// Still ZERO __syncthreads in the level kernels.

typedef __attribute__((ext_vector_type(8))) short short8;
typedef __attribute__((ext_vector_type(4))) float f32x4;

__device__ __forceinline__ unsigned short f2bf(float x) {
    unsigned u = __float_as_uint(x);
    u += 0x7fffu + ((u >> 16) & 1u);   // round-to-nearest-even
    return (unsigned short)(u >> 16);
}
__device__ __forceinline__ float bf2f(unsigned short b) {
    return __uint_as_float(((unsigned)b) << 16);
}
__device__ __forceinline__ float rcp_fast(float x) { return __builtin_amdgcn_rcpf(x); }
__device__ __forceinline__ float sigm(float x) { return rcp_fast(1.f + __expf(-x)); }
__device__ __forceinline__ float tanh_fast(float x) {
    float e = __expf(2.f * x);
    return (e - 1.f) * rcp_fast(e + 1.f);
}

// ---------------------------------------------------------------------------
// Pack W_iou (384x256) -> Wl ; [U_iou (384x256); U_f (256x256)] -> Wc (640x256)
__global__ __launch_bounds__(256)
void prep_kernel(const float* __restrict__ W_iou,
                 const float* __restrict__ U_iou,
                 const float* __restrict__ U_f,
                 unsigned short* __restrict__ Wl,
                 unsigned short* __restrict__ Wc)
{
    const int i = blockIdx.x * 256 + threadIdx.x;   // grid covers 98304
    if (i < 98304) {
        Wl[i] = f2bf(W_iou[i]);
        Wc[i] = f2bf(U_iou[i]);
    }
    if (i < 65536) {
        Wc[98304 + i] = f2bf(U_f[i]);
    }
}

// ---------------------------------------------------------------------------
// Id chase: dst[2i],dst[2i+1] = cp[ src[i] or srcBase+i ]
__global__ __launch_bounds__(256)
void chase_kernel(const int2* __restrict__ cp, const int* __restrict__ src,
                  int srcBase, int n, int* __restrict__ dst)
{
    const int i = blockIdx.x * 256 + threadIdx.x;
    if (i < n) {
        const int s = src ? src[i] : srcBase + i;
        const int2 c = cp[s];
        dst[2 * i]     = c.x;
        dst[2 * i + 1] = c.y;
    }
}

// ---------------------------------------------------------------------------
// One wave = 16 nodes of one level; no barriers. mfma(A=nodes, B=W):
// A row = lane&15 (node), B col = lane&15 (p), k = ks*32 + (lane>>4)*8.
// D: col(lane&15) = p, rows (lane>>4)*4+r = node. 8 p-slices looped.
// h/c staged per-wave in LDS [16 nodes][128 p] bf16 tiles, flushed coalesced.
template<int NCOL, bool LEAF, bool STORE_HC>
__global__ __launch_bounds__(256)
void wave_level(const unsigned short* __restrict__ Wg,  // [NCOL*128][256] bf16
                const int*  __restrict__ idlist,        // local->global (or null)
                int idbase,
                const int*  __restrict__ leafx,         // LEAF only
                const float* __restrict__ emb,          // LEAF only
                const unsigned short* __restrict__ hprev,
                const unsigned short* __restrict__ cprev,
                unsigned short* __restrict__ hout,
                unsigned short* __restrict__ cout,
                const float* __restrict__ b_iou,
                const float* __restrict__ b_f,
                const float* __restrict__ W_lin,
                const float* __restrict__ b_lin,
                float* __restrict__ out, int segOff, int nnodes)
{
    __shared__ unsigned char stg[4][8192];   // per-wave: h tile 4KB | c tile 4KB

    const int lane = threadIdx.x & 63;
    const int widx = threadIdx.x >> 6;
    const int nb   = (blockIdx.x * 4 + widx) * 16;   // local node base
    if (nb >= nnodes) return;
    const int lrow = lane & 15;
    const int lk   = lane >> 4;

    unsigned short* sh = (unsigned short*)(stg[widx]);          // [16][128]
    unsigned short* sc = (unsigned short*)(stg[widx] + 4096);   // [16][128]

    // ---- A fragments: node (lane&15)'s 16B at k = ks*32 + lk*8, all 8 ks ----
    short8 aN[8];
    if (LEAF) {
        const int li = idlist ? idlist[nb + lrow] : idbase + nb + lrow;
        const int gi = leafx[li];
        const float* er = emb + (size_t)gi * 256;
        #pragma unroll
        for (int ks = 0; ks < 8; ++ks) {
            const float4 a = *reinterpret_cast<const float4*>(er + ks * 32 + lk * 8);
            const float4 b = *reinterpret_cast<const float4*>(er + ks * 32 + lk * 8 + 4);
            short8 v;
            v[0]=(short)f2bf(a.x); v[1]=(short)f2bf(a.y);
            v[2]=(short)f2bf(a.z); v[3]=(short)f2bf(a.w);
            v[4]=(short)f2bf(b.x); v[5]=(short)f2bf(b.y);
            v[6]=(short)f2bf(b.z); v[7]=(short)f2bf(b.w);
            aN[ks] = v;
        }
    } else {
        #pragma unroll
        for (int ks = 0; ks < 8; ++ks) {
            const int child = 2 * (nb + lrow) + (ks >= 4 ? 1 : 0);
            aN[ks] = *reinterpret_cast<const short8*>(
                hprev + (size_t)child * 128 + (ks & 3) * 32 + lk * 8);
        }
    }

    // global out-ids for the 4 nodes this lane owns in D
    int gidr[4];
    #pragma unroll
    for (int r = 0; r < 4; ++r) {
        const int i = nb + lk * 4 + r;
        gidr[r] = idlist ? idlist[i] : idbase + i;
    }

    float lgt[5][4];
    #pragma unroll
    for (int cl = 0; cl < 5; ++cl)
        #pragma unroll
        for (int r = 0; r < 4; ++r) lgt[cl][r] = 0.f;

    for (int pb = 0; pb < 128; pb += 16) {
        f32x4 acc[NCOL];
        #pragma unroll
        for (int j = 0; j < NCOL; ++j) acc[j] = (f32x4){0.f, 0.f, 0.f, 0.f};

        #pragma unroll
        for (int ks = 0; ks < 8; ++ks) {
            short8 bW[NCOL];
            #pragma unroll
            for (int j = 0; j < NCOL; ++j)
                bW[j] = *reinterpret_cast<const short8*>(
                    Wg + (size_t)(j * 128 + pb + lrow) * 256 + ks * 32 + lk * 8);
            #pragma unroll
            for (int j = 0; j < NCOL; ++j)
                acc[j] = __builtin_amdgcn_mfma_f32_16x16x32_bf16(
                    aN[ks], bW[j], acc[j], 0, 0, 0);
        }

        const int p = pb + lrow;
        const float bi = b_iou[p], bo = b_iou[128 + p], bu = b_iou[256 + p];
        float bf0 = 0.f, bf1 = 0.f;
        if (NCOL == 5) { bf0 = b_f[p]; bf1 = b_f[128 + p]; }
        float wl[5];
        #pragma unroll
        for (int cl = 0; cl < 5; ++cl) wl[cl] = W_lin[cl * 128 + p];

        #pragma unroll
        for (int r = 0; r < 4; ++r) {
            const int i = nb + lk * 4 + r;
            const float iv = acc[0][r] + bi;
            const float ov = acc[1][r] + bo;
            const float uv = acc[2][r] + bu;
            float csum = 0.f;
            if (NCOL == 5) {
                const float c0 = bf2f(cprev[(size_t)(2 * i) * 128 + p]);
                const float c1 = bf2f(cprev[(size_t)(2 * i + 1) * 128 + p]);
                csum = sigm(acc[3][r] + bf0) * c0 + sigm(acc[4][r] + bf1) * c1;
            }
            const float cv = sigm(iv) * tanh_fast(uv) + csum;
            const float hv = sigm(ov) * tanh_fast(cv);
            if (STORE_HC) {
                const int tl = (lk * 4 + r) * 128 + p;   // [node][p] in tile
                sh[tl] = f2bf(hv);
                sc[tl] = f2bf(cv);
            }
            #pragma unroll
            for (int cl = 0; cl < 5; ++cl) lgt[cl][r] += hv * wl[cl];
        }
    }

    // ---- coalesced flush of this wave's 16-node h/c tiles (wave-local,
    //      compiler inserts the lgkmcnt waits; no barrier needed) ----
    if (STORE_HC) {
        #pragma unroll
        for (int q = 0; q < 4; ++q) {
            const int off = q * 1024 + lane * 16;            // byte in 4KB tile
            const size_t didx = (size_t)(nb + (off >> 8)) * 128 + ((off & 255) >> 1);
            short8 vh = *reinterpret_cast<const short8*>(
                reinterpret_cast<const unsigned char*>(sh) + off);
            *reinterpret_cast<short8*>(hout + didx) = vh;
            short8 vc = *reinterpret_cast<const short8*>(
                reinterpret_cast<const unsigned char*>(sc) + off);
            *reinterpret_cast<short8*>(cout + didx) = vc;
        }
    }

    // ---- logits: butterfly-reduce over the 16-lane p-group, then write ----
    #pragma unroll
    for (int cl = 0; cl < 5; ++cl)
        #pragma unroll
        for (int r = 0; r < 4; ++r) {
            float d = lgt[cl][r];
            d += __shfl_xor(d, 1);
            d += __shfl_xor(d, 2);
            d += __shfl_xor(d, 4);
            d += __shfl_xor(d, 8);
            lgt[cl][r] = d;
        }
    if (lrow < 5) {
        const float bl = b_lin[lrow];
        #pragma unroll
        for (int r = 0; r < 4; ++r) {
            float v = (lrow == 0) ? lgt[0][r] : (lrow == 1) ? lgt[1][r]
                    : (lrow == 2) ? lgt[2][r] : (lrow == 3) ? lgt[3][r] : lgt[4][r];
            out[(size_t)(segOff + gidr[r]) * 5 + lrow] = v + bl;
        }
    }
}

// ===========================================================================
// Fallback (ws too small): v7 fused subtree kernel — measured 903us, passed.
// ===========================================================================
#define FB_THREADS 512

template<int NCOL, int G, int CW, bool WC>
__device__ __forceinline__ void fb_level_step(
    const unsigned short* __restrict__ Wg,
    const unsigned char* Blds, unsigned char* h_out, unsigned short* cAr,
    const float* __restrict__ b_iou, const float* __restrict__ b_f,
    int w, int lrow, int lk, int slotBase, int mrows)
{
    const int q0 = w * 16;
    const unsigned char* wbase = reinterpret_cast<const unsigned char*>(Wg)
                               + (q0 + lrow) * 512 + lk * 16;
    f32x4 acc[NCOL][G];
    #pragma unroll
    for (int j = 0; j < NCOL; ++j)
        #pragma unroll
        for (int g = 0; g < G; ++g) acc[j][g] = (f32x4){0.f, 0.f, 0.f, 0.f};
    #pragma unroll
    for (int ks = 0; ks < 8; ++ks) {
        short8 aW[NCOL];
        #pragma unroll
        for (int j = 0; j < NCOL; ++j)
            aW[j] = *reinterpret_cast<const short8*>(wbase + j * 65536 + ks * 64);
        #pragma unroll
        for (int g = 0; g < G; ++g) {
            const int row = g * 16 + lrow;
            const int chunk = (ks * 4 + lk) ^ (row & 7);
            short8 bN = *reinterpret_cast<const short8*>(
                Blds + row * 512 + (chunk << 4));
            #pragma unroll
            for (int j = 0; j < NCOL; ++j)
                acc[j][g] = __builtin_amdgcn_mfma_f32_16x16x32_bf16(
                    aW[j], bN, acc[j][g], 0, 0, 0);
        }
    }
    #pragma unroll
    for (int g = 0; g < G; ++g) {
        const int mlB = g * 16 + lrow;
        if (mlB < mrows) {
            const int ml = slotBase + mlB;
            #pragma unroll
            for (int r = 0; r < 4; ++r) {
                const int p = q0 + lk * 4 + r;
                float iv = acc[0][g][r] + b_iou[p];
                float ov = acc[1][g][r] + b_iou[128 + p];
                float uv = acc[2][g][r] + b_iou[256 + p];
                float csum = 0.f;
                if (NCOL == 5) {
                    float f0 = acc[3][g][r] + b_f[p];
                    float f1 = acc[4][g][r] + b_f[128 + p];
                    const int cb = p * 66 + CW * mlB;
                    csum = sigm(f0) * bf2f(cAr[cb]) + sigm(f1) * bf2f(cAr[cb + CW / 2]);
                }
                float cv = sigm(iv) * tanh_fast(uv) + csum;
                float hv = sigm(ov) * tanh_fast(cv);
                if (WC) cAr[p * 66 + CW * ml] = f2bf(cv);
                const int jr = ml >> 1;
                const int q = (ml & 1) * 16 + (p >> 3);
                *reinterpret_cast<unsigned short*>(
                    h_out + jr * 512 + ((q ^ (jr & 7)) << 4) + (p & 7) * 2) = f2bf(hv);
            }
        }
    }
}

__device__ __forceinline__ void fb_logits_emit(
    const unsigned char* h_lds, int M, const int* idsLds, int idBase,
    int segOff, const float* __restrict__ W_lin, const float* __restrict__ b_lin,
    float* __restrict__ out, int t)
{
    const int s = t >> 2, sub = t & 3;
    if (s >= M) return;
    float hv[32];
    const int j = s >> 1;
    #pragma unroll
    for (int qq = 0; qq < 4; ++qq) {
        const int q = (s & 1) * 16 + sub * 4 + qq;
        short8 v = *reinterpret_cast<const short8*>(
            h_lds + j * 512 + ((q ^ (j & 7)) << 4));
        #pragma unroll
        for (int e = 0; e < 8; ++e) hv[qq * 8 + e] = bf2f((unsigned short)v[e]);
    }
    const int gid = idsLds ? idsLds[s] : (idBase + s);
    float dots[5];
    #pragma unroll
    for (int cl = 0; cl < 5; ++cl) {
        const float* wr = W_lin + cl * 128 + sub * 32;
        float d = 0.f;
        #pragma unroll
        for (int k = 0; k < 32; ++k) d += hv[k] * wr[k];
        d += __shfl_xor(d, 1);
        d += __shfl_xor(d, 2);
        dots[cl] = d;
    }
    if (sub == 0) {
        float* op = out + (size_t)(segOff + gid) * 5;
        #pragma unroll
        for (int cl = 0; cl < 5; ++cl) op[cl] = dots[cl] + b_lin[cl];
    }
}

__global__ __launch_bounds__(FB_THREADS, 4)
void fb_tree_kernel(const int*  __restrict__ leaf_x,
                    const int2* __restrict__ cpairs,
                    const float* __restrict__ emb,
                    const unsigned short* __restrict__ Wl,
                    const unsigned short* __restrict__ Wc,
                    const float* __restrict__ b_iou,
                    const float* __restrict__ b_f,
                    const float* __restrict__ W_lin,
                    const float* __restrict__ b_lin,
                    float* __restrict__ out)
{
    __shared__ __align__(16) unsigned char arena[49664];
    __shared__ int ids0[64], ids1[32], ids2[16], tok[64];
    const int t = threadIdx.x, lane = t & 63, w = t >> 6;
    const int lrow = lane & 15, lk = lane >> 4;
    const int blk3 = blockIdx.x * 8;
    if (t < 8)  { int2 p = cpairs[196608 + blk3 + t]; ids2[2*t] = p.x; ids2[2*t+1] = p.y; }
    __syncthreads();
    if (t < 16) { int2 p = cpairs[131072 + ids2[t]];  ids1[2*t] = p.x; ids1[2*t+1] = p.y; }
    __syncthreads();
    if (t < 32) { int2 p = cpairs[ids1[t]];           ids0[2*t] = p.x; ids0[2*t+1] = p.y; }
    __syncthreads();
    if (t < 64) { tok[t] = leaf_x[ids0[t]]; }
    __syncthreads();
    unsigned char*  X0  = arena;
    unsigned char*  h0  = arena + 16384;
    unsigned short* cAr = (unsigned short*)(arena + 32768);
    unsigned char*  h1  = arena;
    unsigned char*  h2  = arena + 16384;
    unsigned char*  h3  = arena + 8192;
    #pragma unroll 1
    for (int half = 0; half < 2; ++half) {
        {
            const int c = t & 31, r0 = t >> 5;
            #pragma unroll
            for (int rr = 0; rr < 2; ++rr) {
                const int r = r0 + rr * 16;
                const int gi = tok[half * 32 + r];
                const float4* src = reinterpret_cast<const float4*>(
                    emb + (size_t)gi * 256 + c * 8);
                float4 a = src[0], b = src[1];
                short8 v;
                v[0]=(short)f2bf(a.x); v[1]=(short)f2bf(a.y);
                v[2]=(short)f2bf(a.z); v[3]=(short)f2bf(a.w);
                v[4]=(short)f2bf(b.x); v[5]=(short)f2bf(b.y);
                v[6]=(short)f2bf(b.z); v[7]=(short)f2bf(b.w);
                *reinterpret_cast<short8*>(X0 + r * 512 + ((c ^ (r & 7)) << 4)) = v;
            }
        }
        __syncthreads();
        fb_level_step<3, 2, 1, true>(Wl, X0, h0, cAr, b_iou, b_f,
                                     w, lrow, lk, half * 32, 32);
        __syncthreads();
    }
    fb_logits_emit(h0, 64, ids0, 0, 0, W_lin, b_lin, out, t);
    fb_level_step<5, 2, 2, true>(Wc, h0, h1, cAr, b_iou, b_f, w, lrow, lk, 0, 32);
    __syncthreads();
    fb_logits_emit(h1, 32, ids1, 0, 262144, W_lin, b_lin, out, t);
    fb_level_step<5, 1, 4, true>(Wc, h1, h2, cAr, b_iou, b_f, w, lrow, lk, 0, 16);
    __syncthreads();
    fb_logits_emit(h2, 16, ids2, 0, 393216, W_lin, b_lin, out, t);
    fb_level_step<5, 1, 8, false>(Wc, h2, h3, cAr, b_iou, b_f, w, lrow, lk, 0, 8);
    __syncthreads();
    fb_logits_emit(h3, 8, nullptr, blk3, 458752, W_lin, b_lin, out, t);
}

// ---------------------------------------------------------------------------
extern "C" void kernel_launch(void* const* d_in, const int* in_sizes, int n_in,
                              void* d_out, int out_size, void* d_ws, size_t ws_size,
                              hipStream_t stream)
{
    const int*   leaf_x = (const int*)d_in[0];
    const int*   child  = (const int*)d_in[1];
    const float* emb    = (const float*)d_in[2];
    const float* W_iou  = (const float*)d_in[3];
    const float* U_iou  = (const float*)d_in[4];
    const float* b_iou  = (const float*)d_in[5];
    const float* U_f    = (const float*)d_in[6];
    const float* b_f    = (const float*)d_in[7];
    const float* W_lin  = (const float*)d_in[8];
    const float* b_lin  = (const float*)d_in[9];
    float* out = (float*)d_out;

    char* ws = (char*)d_ws;
    unsigned short* Wl = (unsigned short*)ws;                 // 192 KiB
    unsigned short* Wc = (unsigned short*)(ws + 196608);      // 320 KiB

    auto need = [](int s) -> size_t {
        const size_t n3 = 32768u / s, n2 = 2 * n3, n1 = 2 * n2, n0 = 2 * n1;
        size_t off = 524288;
        off += (n0 + n1 + n2) * 4;            // ids
        off = (off + 255) & ~(size_t)255;
        off += (n0 + n0 + n1 + n1) * 256;     // h0,c0,h1,c1 (256 B per node)
        return off;
    };
    int s = 0;
    if      (ws_size >= need(1)) s = 1;
    else if (ws_size >= need(2)) s = 2;
    else if (ws_size >= need(4)) s = 4;

    prep_kernel<<<384, 256, 0, stream>>>(W_iou, U_iou, U_f, Wl, Wc);

    if (s == 0) {
        fb_tree_kernel<<<4096, FB_THREADS, 0, stream>>>(
            leaf_x, (const int2*)child, emb, Wl, Wc,
            b_iou, b_f, W_lin, b_lin, out);
        return;
    }

    const int n3 = 32768 / s, n2 = 2 * n3, n1 = 2 * n2, n0 = 2 * n1;
    size_t off = 524288;
    int* ids0 = (int*)(ws + off); off += (size_t)n0 * 4;
    int* ids1 = (int*)(ws + off); off += (size_t)n1 * 4;
    int* ids2 = (int*)(ws + off); off += (size_t)n2 * 4;
    off = (off + 255) & ~(size_t)255;
    unsigned short* h0 = (unsigned short*)(ws + off); off += (size_t)n0 * 256;
    unsigned short* c0 = (unsigned short*)(ws + off); off += (size_t)n0 * 256;
    unsigned short* h1 = (unsigned short*)(ws + off); off += (size_t)n1 * 256;
    unsigned short* c1 = (unsigned short*)(ws + off);
    unsigned short* h2 = h0;   // leaf buffers dead once L1 written
    unsigned short* c2 = c0;

    const int2* cp = (const int2*)child;
    for (int sp = 0; sp < s; ++sp) {
        const int r3 = sp * n3;
        chase_kernel<<<(n3 + 255) / 256, 256, 0, stream>>>(cp + 196608, nullptr, r3, n3, ids2);
        chase_kernel<<<(n2 + 255) / 256, 256, 0, stream>>>(cp + 131072, ids2, 0, n2, ids1);
        chase_kernel<<<(n1 + 255) / 256, 256, 0, stream>>>(cp,          ids1, 0, n1, ids0);

        wave_level<3, true, true><<<n0 / 64, 256, 0, stream>>>(
            Wl, ids0, 0, leaf_x, emb, nullptr, nullptr, h0, c0,
            b_iou, b_f, W_lin, b_lin, out, 0, n0);
        wave_level<5, false, true><<<n1 / 64, 256, 0, stream>>>(
            Wc, ids1, 0, nullptr, nullptr, h0, c0, h1, c1,
            b_iou, b_f, W_lin, b_lin, out, 262144, n1);
        wave_level<5, false, true><<<n2 / 64, 256, 0, stream>>>(
            Wc, ids2, 0, nullptr, nullptr, h1, c1, h2, c2,
            b_iou, b_f, W_lin, b_lin, out, 393216, n2);
        wave_level<5, false, false><<<n3 / 64, 256, 0, stream>>>(
            Wc, nullptr, r3, nullptr, nullptr, h2, c2, nullptr, nullptr,
            b_iou, b_f, W_lin, b_lin, out, 458752, n3);
    }
}